// Round 8
// baseline (628.417 us; speedup 1.0000x reference)
//
#include <hip/hip_runtime.h>

#define HH   128
#define H2   256
#define H3   384
#define NPT  65535      // nodes per tree (2^16 - 1)
#define MT   32         // nodes per tile
#define TPB  512        // 8 waves

typedef __bf16 bf16x8 __attribute__((ext_vector_type(8)));
typedef float  f32x4  __attribute__((ext_vector_type(4)));

__device__ unsigned short Wb_g[640 * 256];   // bf16 [row=output col j][k]; j<384: W_iou, else W_f

__device__ __forceinline__ float fsig(float x)  { return 1.0f / (1.0f + __expf(-x)); }
__device__ __forceinline__ float ftanh(float x) { return 1.0f - 2.0f / (__expf(2.0f * x) + 1.0f); }
__device__ __forceinline__ unsigned short f2bf(float f) {   // RNE fp32->bf16
    unsigned u = __float_as_uint(f);
    u += 0x7fffu + ((u >> 16) & 1u);
    return (unsigned short)(u >> 16);
}
__device__ __forceinline__ int swz(int off) { return off ^ (((off >> 9) & 7) << 4); }

// ---------------- weight convert: fp32 -> bf16, once per launch ----------------
__global__ __launch_bounds__(256) void conv_k(const float* __restrict__ W_iou,
                                              const float* __restrict__ W_f)
{
    int t    = blockIdx.x * 256 + threadIdx.x;
    int base = t * 4;
    int j = base >> 8, k = base & 255;
    const float* src = (j < H3) ? (W_iou + (size_t)j * H2 + k)
                                : (W_f + (size_t)(j - H3) * H2 + k);
    float4 v = *(const float4*)src;
    ushort4 p;
    p.x = f2bf(v.x); p.y = f2bf(v.y); p.z = f2bf(v.z); p.w = f2bf(v.w);
    *(ushort4*)(Wb_g + base) = p;
}

// ---------------- leaf frontier: elementwise only ----------------
__global__ __launch_bounds__(256) void leaf_k(
    const float* __restrict__ iou, const float* __restrict__ c_in,
    const float* __restrict__ b_iou,
    float* __restrict__ h_out, float* __restrict__ c_ws,
    unsigned short* __restrict__ h_bf)
{
    int g    = blockIdx.x * 256 + threadIdx.x;
    int node = g >> 5;                           // 131072 leaf nodes
    int e    = (g & 31) << 2;
    int tree = node >> 15;
    int loc  = 32767 + (node & 32767);
    size_t row = (size_t)tree * NPT + loc;

    const float* ip = iou + row * H3;
    float4 vi = *(const float4*)(ip + e);
    float4 vo = *(const float4*)(ip + HH + e);
    float4 vu = *(const float4*)(ip + 2 * HH + e);
    float4 vc = *(const float4*)(c_in + row * HH + e);
    float4 bi = *(const float4*)(b_iou + e);
    float4 bo = *(const float4*)(b_iou + HH + e);
    float4 bu = *(const float4*)(b_iou + 2 * HH + e);

    float4 hn, cn;
#define DOL(X) { float iv = fsig(vi.X + bi.X); float ov = fsig(vo.X + bo.X); \
                 float uv = ftanh(vu.X + bu.X); float cv = iv * uv + vc.X;   \
                 cn.X = cv; hn.X = ov * ftanh(cv); }
    DOL(x) DOL(y) DOL(z) DOL(w)
#undef DOL
    *(float4*)(h_out + row * HH + e) = hn;
    *(float4*)(c_ws  + row * HH + e) = cn;
    ushort4 hb;
    hb.x = f2bf(hn.x); hb.y = f2bf(hn.y); hb.z = f2bf(hn.z); hb.w = f2bf(hn.w);
    *(ushort4*)(h_bf + row * HH + e) = hb;
}

// ---------------- MFMA over one 32-node swizzled LDS tile ----------------
__device__ __forceinline__ void mfma_from(const unsigned char* tile,
                                          const unsigned short* Wp,
                                          f32x4 acc[2][5], int lr, int lc)
{
#pragma unroll
    for (int kk = 0; kk < 8; ++kk) {
        bf16x8 a0 = *(const bf16x8*)(tile + swz(lr * 512 + kk * 64 + lc * 16));
        bf16x8 a1 = *(const bf16x8*)(tile + swz((16 + lr) * 512 + kk * 64 + lc * 16));
#pragma unroll
        for (int g = 0; g < 5; ++g) {
            bf16x8 b = *(const bf16x8*)(Wp + (size_t)g * HH * H2 + kk * 32);
            acc[0][g] = __builtin_amdgcn_mfma_f32_16x16x32_bf16(a0, b, acc[0][g], 0, 0, 0);
            acc[1][g] = __builtin_amdgcn_mfma_f32_16x16x32_bf16(a1, b, acc[1][g], 0, 0, 0);
        }
    }
}

#define GATES(AC, MTI, RI, CL, CR, HV, CV) \
    { float pi = AC[MTI][0][RI] + bi, po = AC[MTI][1][RI] + bo, pu = AC[MTI][2][RI] + bu; \
      float pl = AC[MTI][3][RI] + bl, pr = AC[MTI][4][RI] + br;                           \
      CV = fsig(pi) * ftanh(pu) + fsig(pl) * (CL) + fsig(pr) * (CR);                      \
      HV = fsig(po) * ftanh(CV); }

// ---------------- fused 3-level subtree: l=ltop+2 (B), ltop+1 (M), ltop (T) ----------------
// Block b owns: B tiles 4b..4b+3, M tiles 2b,2b+1, T tile b. Intermediate h/c live
// in LDS; only T writes c_ws/h_bf to global. Schedule: B0 B1 M0 B2 B3 M1 T.
__global__ __launch_bounds__(TPB, 4) void fuse_k(
    int ltop,
    const float* __restrict__ b_iou, const float* __restrict__ b_f,
    float* __restrict__ h_g, float* __restrict__ c_ws,
    unsigned short* __restrict__ h_bf)
{
    __shared__ __align__(16) unsigned char As[16384];   // staging for B tiles
    __shared__ __align__(16) unsigned char hm[16384];   // B outputs, M-tile A-layout (per tm)
    __shared__ __align__(16) _Float16     cm[64 * 128]; // B outputs c (per tm)
    __shared__ __align__(16) unsigned char ht[16384];   // M outputs, T-tile A-layout
    __shared__ __align__(16) _Float16     ct[64 * 128]; // M outputs c

    const int tid = threadIdx.x;
    const int w = tid >> 6, lr = tid & 15, lc = (tid & 63) >> 4;
    const int ee = w * 16 + lr;
    const int b  = blockIdx.x;
    const int lb = ltop + 2, lm = ltop + 1;
    const float bi = b_iou[ee], bo = b_iou[HH + ee], bu = b_iou[2 * HH + ee];
    const float bl = b_f[ee],   br = b_f[HH + ee];
    const unsigned short* Wp = Wb_g + (size_t)ee * H2 + lc * 8;

#pragma unroll 1
    for (int tm = 0; tm < 2; ++tm) {
#pragma unroll 1
        for (int ib = 0; ib < 2; ++ib) {
            const int i = tm * 2 + ib;          // bottom tile 0..3
            __syncthreads();   // As free (prev MFMA done); hm/cm free (prev M done)

            // ---- stage B children from global h_bf ----
#pragma unroll
            for (int it = 0; it < 2; ++it) {
                int item = tid + TPB * it;
                int m = item >> 5, u = item & 31;
                int node = b * 128 + i * 32 + m;
                int tree = node >> lb;
                int loc  = ((1 << lb) - 1) + (node & ((1 << lb) - 1));
                size_t crow = (size_t)tree * NPT + 2 * loc + 1 + (u >> 4);
                uint4 v = *(const uint4*)(h_bf + crow * HH + (u & 15) * 8);
                *(uint4*)(As + swz(m * 512 + u * 16)) = v;
            }
            __syncthreads();

            f32x4 acc[2][5] = {};
            mfma_from(As, Wp, acc, lr, lc);

            // batched global child-c loads
            float clv[2][4], crv[2][4];
#pragma unroll
            for (int mt = 0; mt < 2; ++mt)
#pragma unroll
                for (int r = 0; r < 4; ++r) {
                    int n_local = i * 32 + mt * 16 + lc * 4 + r;
                    int node = b * 128 + n_local;
                    int tree = node >> lb;
                    int loc  = ((1 << lb) - 1) + (node & ((1 << lb) - 1));
                    size_t lrow = (size_t)tree * NPT + 2 * loc + 1;
                    clv[mt][r] = c_ws[lrow * HH + ee];
                    crv[mt][r] = c_ws[(lrow + 1) * HH + ee];
                }
#pragma unroll
            for (int mt = 0; mt < 2; ++mt)
#pragma unroll
                for (int r = 0; r < 4; ++r) {
                    int n_local = i * 32 + mt * 16 + lc * 4 + r;
                    int node = b * 128 + n_local;
                    int tree = node >> lb;
                    int loc  = ((1 << lb) - 1) + (node & ((1 << lb) - 1));
                    size_t row = (size_t)tree * NPT + loc;
                    float hv, cv;
                    GATES(acc, mt, r, clv[mt][r], crv[mt][r], hv, cv);
                    h_g[row * HH + ee] = hv;
                    int m_in = (n_local >> 1) & 31, half = n_local & 1;
                    *(unsigned short*)(hm + swz(m_in * 512 + ((half << 7) + ee) * 2)) = f2bf(hv);
                    cm[((n_local & 63) << 7) + ee] = (_Float16)cv;
                }
        }

        // ---- M tile tm: children entirely in LDS ----
        __syncthreads();
        {
            f32x4 acc[2][5] = {};
            mfma_from(hm, Wp, acc, lr, lc);
#pragma unroll
            for (int mt = 0; mt < 2; ++mt)
#pragma unroll
                for (int r = 0; r < 4; ++r) {
                    int q  = mt * 16 + lc * 4 + r;        // 0..31 within M tile
                    int ml = tm * 32 + q;                 // mid-local 0..63
                    int node = b * 64 + ml;
                    int tree = node >> lm;
                    int loc  = ((1 << lm) - 1) + (node & ((1 << lm) - 1));
                    size_t row = (size_t)tree * NPT + loc;
                    float cl = (float)cm[((2 * q) << 7) + ee];
                    float cr = (float)cm[((2 * q + 1) << 7) + ee];
                    float hv, cv;
                    GATES(acc, mt, r, cl, cr, hv, cv);
                    h_g[row * HH + ee] = hv;
                    int j = ml >> 1, half = ml & 1;
                    *(unsigned short*)(ht + swz(j * 512 + ((half << 7) + ee) * 2)) = f2bf(hv);
                    ct[(ml << 7) + ee] = (_Float16)cv;
                }
        }
    }

    // ---- T tile: children in LDS; writes global c_ws/h_bf for next launch ----
    __syncthreads();
    {
        f32x4 acc[2][5] = {};
        mfma_from(ht, Wp, acc, lr, lc);
#pragma unroll
        for (int mt = 0; mt < 2; ++mt)
#pragma unroll
            for (int r = 0; r < 4; ++r) {
                int j = mt * 16 + lc * 4 + r;             // 0..31
                int node = b * 32 + j;
                int tree = node >> ltop;
                int loc  = ((1 << ltop) - 1) + (node & ((1 << ltop) - 1));
                size_t row = (size_t)tree * NPT + loc;
                float cl = (float)ct[((2 * j) << 7) + ee];
                float cr = (float)ct[((2 * j + 1) << 7) + ee];
                float hv, cv;
                GATES(acc, mt, r, cl, cr, hv, cv);
                h_g[row * HH + ee]  = hv;
                c_ws[row * HH + ee] = cv;
                h_bf[row * HH + ee] = f2bf(hv);
            }
    }
}

// ---------------- solo tail l=5..0: one block per tree, weights in registers ----------------
__global__ __launch_bounds__(TPB, 2) void solo_k(
    const float* __restrict__ b_iou, const float* __restrict__ b_f,
    float* __restrict__ h_g, float* __restrict__ c_ws,
    const unsigned short* __restrict__ h_bf)
{
    __shared__ __align__(16) unsigned char hb[32768];

    const int tid = threadIdx.x;
    const int w = tid >> 6, lr = tid & 15, lc = (tid & 63) >> 4;
    const int ee = w * 16 + lr;
    const size_t tb = (size_t)blockIdx.x * NPT;
    const float bi = b_iou[ee], bo = b_iou[HH + ee], bu = b_iou[2 * HH + ee];
    const float bl = b_f[ee],   br = b_f[HH + ee];

    bf16x8 Bf[5][8];
    const unsigned short* Wp = Wb_g + (size_t)ee * H2 + lc * 8;
#pragma unroll
    for (int g = 0; g < 5; ++g)
#pragma unroll
        for (int kk = 0; kk < 8; ++kk)
            Bf[g][kk] = *(const bf16x8*)(Wp + (size_t)g * HH * H2 + kk * 32);

#pragma unroll
    for (int it = 0; it < 2; ++it) {
        int p = tid + TPB * it;
        int cc = p >> 4, q = p & 15;
        uint4 v = *(const uint4*)(h_bf + (tb + 63 + cc) * HH + q * 8);
        *(uint4*)(hb + swz(p * 16)) = v;
    }

#pragma unroll 1
    for (int l = 5; l >= 0; --l) {
        const int nl     = 1 << l;
        const int loc0   = nl - 1;
        const int cloc0  = 2 * nl - 1;
        const int cbase  = (l & 1) ? 0 : 16384;
        const int obase  = cbase ^ 16384;
        const bool mt1   = (nl > 16);

        __syncthreads();

        f32x4 acc[2][5] = {};
#pragma unroll
        for (int kk = 0; kk < 8; ++kk) {
            bf16x8 a0 = *(const bf16x8*)(hb + cbase + swz(lr * 512 + kk * 64 + lc * 16));
#pragma unroll
            for (int g = 0; g < 5; ++g)
                acc[0][g] = __builtin_amdgcn_mfma_f32_16x16x32_bf16(a0, Bf[g][kk], acc[0][g], 0, 0, 0);
            if (mt1) {
                bf16x8 a1 = *(const bf16x8*)(hb + cbase + swz((16 + lr) * 512 + kk * 64 + lc * 16));
#pragma unroll
                for (int g = 0; g < 5; ++g)
                    acc[1][g] = __builtin_amdgcn_mfma_f32_16x16x32_bf16(a1, Bf[g][kk], acc[1][g], 0, 0, 0);
            }
        }
        __syncthreads();

#pragma unroll
        for (int mt = 0; mt < 2; ++mt)
#pragma unroll
            for (int r = 0; r < 4; ++r) {
                int j = mt * 16 + lc * 4 + r;
                if (j >= nl) continue;
                size_t row  = tb + loc0 + j;
                size_t lrow = tb + cloc0 + 2 * j;
                float hv, cv;
                GATES(acc, mt, r, c_ws[lrow * HH + ee], c_ws[(lrow + 1) * HH + ee], hv, cv);
                h_g[row * HH + ee]  = hv;
                c_ws[row * HH + ee] = cv;
                *(unsigned short*)(hb + obase + swz(j * 256 + ee * 2)) = f2bf(hv);
            }
    }
}

extern "C" void kernel_launch(void* const* d_in, const int* in_sizes, int n_in,
                              void* d_out, int out_size, void* d_ws, size_t ws_size,
                              hipStream_t stream)
{
    const float* iou   = (const float*)d_in[0];
    const float* c_in  = (const float*)d_in[2];
    const float* W_iou = (const float*)d_in[3];
    const float* b_iou = (const float*)d_in[4];
    const float* W_f   = (const float*)d_in[5];
    const float* b_f   = (const float*)d_in[6];
    float* h_out = (float*)d_out;
    float* c_ws  = (float*)d_ws;                                                        // 134 MiB fp32 c
    unsigned short* h_bf = (unsigned short*)((char*)d_ws + (size_t)136 * 1024 * 1024);  // 67 MiB bf16 h

    conv_k<<<160, 256, 0, stream>>>(W_iou, W_f);
    leaf_k<<<16384, 256, 0, stream>>>(iou, c_in, b_iou, h_out, c_ws, h_bf);

    fuse_k<<<512, TPB, 0, stream>>>(12, b_iou, b_f, h_out, c_ws, h_bf);   // l=14,13,12
    fuse_k<<< 64, TPB, 0, stream>>>( 9, b_iou, b_f, h_out, c_ws, h_bf);   // l=11,10,9
    fuse_k<<<  8, TPB, 0, stream>>>( 6, b_iou, b_f, h_out, c_ws, h_bf);   // l=8,7,6
    solo_k<<<  4, TPB, 0, stream>>>(b_iou, b_f, h_out, c_ws, h_bf);       // l=5..0
}

// Round 9
// 484.757 us; speedup vs baseline: 1.2964x; 1.2964x over previous
//
#include <hip/hip_runtime.h>

#define HH   128
#define H2   256
#define H3   384
#define NPT  65535      // nodes per tree (2^16 - 1)
#define MT   32         // nodes per tile
#define TPB  512        // 8 waves

typedef __bf16    bf16x8 __attribute__((ext_vector_type(8)));
typedef float     f32x4  __attribute__((ext_vector_type(4)));
typedef _Float16  f16x4  __attribute__((ext_vector_type(4)));
typedef _Float16  half_t;

__device__ unsigned short Wb_g[640 * 256];   // bf16 [row=output col j][k]; j<384: W_iou, else W_f

__device__ __forceinline__ float fsig(float x)  { return 1.0f / (1.0f + __expf(-x)); }
__device__ __forceinline__ float ftanh(float x) { return 1.0f - 2.0f / (__expf(2.0f * x) + 1.0f); }
__device__ __forceinline__ unsigned short f2bf(float f) {   // RNE fp32->bf16
    unsigned u = __float_as_uint(f);
    u += 0x7fffu + ((u >> 16) & 1u);
    return (unsigned short)(u >> 16);
}
__device__ __forceinline__ int swz(int off) { return off ^ (((off >> 9) & 7) << 4); }

// ---------------- weight convert ----------------
__global__ __launch_bounds__(256) void conv_k(const float* __restrict__ W_iou,
                                              const float* __restrict__ W_f)
{
    int t    = blockIdx.x * 256 + threadIdx.x;
    int base = t * 4;
    int j = base >> 8, k = base & 255;
    const float* src = (j < H3) ? (W_iou + (size_t)j * H2 + k)
                                : (W_f + (size_t)(j - H3) * H2 + k);
    float4 v = *(const float4*)src;
    ushort4 p;
    p.x = f2bf(v.x); p.y = f2bf(v.y); p.z = f2bf(v.z); p.w = f2bf(v.w);
    *(ushort4*)(Wb_g + base) = p;
}

// ---------------- leaf frontier ----------------
__global__ __launch_bounds__(256) void leaf_k(
    const float* __restrict__ iou, const float* __restrict__ c_in,
    const float* __restrict__ b_iou,
    float* __restrict__ h_out, half_t* __restrict__ c_ws,
    unsigned short* __restrict__ h_bf)
{
    int g    = blockIdx.x * 256 + threadIdx.x;
    int node = g >> 5;                           // 131072 leaf nodes
    int e    = (g & 31) << 2;
    int tree = node >> 15;
    int loc  = 32767 + (node & 32767);
    size_t row = (size_t)tree * NPT + loc;

    const float* ip = iou + row * H3;
    float4 vi = *(const float4*)(ip + e);
    float4 vo = *(const float4*)(ip + HH + e);
    float4 vu = *(const float4*)(ip + 2 * HH + e);
    float4 vc = *(const float4*)(c_in + row * HH + e);
    float4 bi = *(const float4*)(b_iou + e);
    float4 bo = *(const float4*)(b_iou + HH + e);
    float4 bu = *(const float4*)(b_iou + 2 * HH + e);

    float4 hn, cn;
#define DOL(X) { float iv = fsig(vi.X + bi.X); float ov = fsig(vo.X + bo.X); \
                 float uv = ftanh(vu.X + bu.X); float cv = iv * uv + vc.X;   \
                 cn.X = cv; hn.X = ov * ftanh(cv); }
    DOL(x) DOL(y) DOL(z) DOL(w)
#undef DOL
    *(float4*)(h_out + row * HH + e) = hn;
    f16x4 cf; cf.x = (half_t)cn.x; cf.y = (half_t)cn.y; cf.z = (half_t)cn.z; cf.w = (half_t)cn.w;
    *(f16x4*)(c_ws + row * HH + e) = cf;
    ushort4 hb;
    hb.x = f2bf(hn.x); hb.y = f2bf(hn.y); hb.z = f2bf(hn.z); hb.w = f2bf(hn.w);
    *(ushort4*)(h_bf + row * HH + e) = hb;
}

// ---------------- MFMA over one 32-node swizzled LDS tile ----------------
__device__ __forceinline__ void mfma_from(const unsigned char* tile,
                                          const unsigned short* Wp,
                                          f32x4 acc[2][5], int lr, int lc)
{
#pragma unroll
    for (int kk = 0; kk < 8; ++kk) {
        bf16x8 a0 = *(const bf16x8*)(tile + swz(lr * 512 + kk * 64 + lc * 16));
        bf16x8 a1 = *(const bf16x8*)(tile + swz((16 + lr) * 512 + kk * 64 + lc * 16));
#pragma unroll
        for (int g = 0; g < 5; ++g) {
            bf16x8 b = *(const bf16x8*)(Wp + (size_t)g * HH * H2 + kk * 32);
            acc[0][g] = __builtin_amdgcn_mfma_f32_16x16x32_bf16(a0, b, acc[0][g], 0, 0, 0);
            acc[1][g] = __builtin_amdgcn_mfma_f32_16x16x32_bf16(a1, b, acc[1][g], 0, 0, 0);
        }
    }
}

#define GATES(AC, MTI, RI, CL, CR, HV, CV) \
    { float pi = AC[MTI][0][RI] + bi, po = AC[MTI][1][RI] + bo, pu = AC[MTI][2][RI] + bu; \
      float pl = AC[MTI][3][RI] + bl, pr = AC[MTI][4][RI] + br;                           \
      CV = fsig(pi) * ftanh(pu) + fsig(pl) * (CL) + fsig(pr) * (CR);                      \
      HV = fsig(po) * ftanh(CV); }

// ---------------- one 32-node tile with global round-trip (l>=6, full tiles) ----------------
__device__ __forceinline__ void do_tile(
    int lvl, int tile,
    float bi, float bo, float bu, float bl, float br,
    float* __restrict__ h_g, half_t* __restrict__ c_ws,
    unsigned short* __restrict__ h_bf,
    unsigned short* A_lds,
    int tid, int w, int lr, int lc, int ee)
{
    const int node0 = tile * MT;
    const int loc0  = (1 << lvl) - 1;
    const int lmask = loc0;

    __syncthreads();

#pragma unroll
    for (int it = 0; it < 2; ++it) {
        int item = tid + TPB * it;
        int m = item >> 5, u = item & 31;
        int node = node0 + m;
        int tree = node >> lvl;
        int loc  = loc0 + (node & lmask);
        size_t crow = (size_t)tree * NPT + 2 * loc + 1 + (u >> 4);
        uint4 v = *(const uint4*)(h_bf + crow * HH + (u & 15) * 8);
        *(uint4*)((char*)A_lds + swz(m * 512 + u * 16)) = v;
    }
    __syncthreads();

    f32x4 acc[2][5] = {};
    const unsigned short* Wp = Wb_g + (size_t)ee * H2 + lc * 8;
    mfma_from((const unsigned char*)A_lds, Wp, acc, lr, lc);

    float clv[2][4], crv[2][4];
#pragma unroll
    for (int mt = 0; mt < 2; ++mt)
#pragma unroll
        for (int r = 0; r < 4; ++r) {
            int node = node0 + mt * 16 + lc * 4 + r;
            int tree = node >> lvl;
            int loc  = loc0 + (node & lmask);
            size_t lrow = (size_t)tree * NPT + 2 * loc + 1;
            clv[mt][r] = (float)c_ws[lrow * HH + ee];
            crv[mt][r] = (float)c_ws[(lrow + 1) * HH + ee];
        }

#pragma unroll
    for (int mt = 0; mt < 2; ++mt)
#pragma unroll
        for (int r = 0; r < 4; ++r) {
            int node = node0 + mt * 16 + lc * 4 + r;
            int tree = node >> lvl;
            int loc  = loc0 + (node & lmask);
            size_t row = (size_t)tree * NPT + loc;
            float hv, cv;
            GATES(acc, mt, r, clv[mt][r], crv[mt][r], hv, cv);
            h_g[row * HH + ee]  = hv;
            c_ws[row * HH + ee] = (half_t)cv;
            h_bf[row * HH + ee] = f2bf(hv);
        }
}

// ---------------- single level ----------------
__global__ __launch_bounds__(TPB, 4) void level_k(
    int lvl,
    const float* __restrict__ b_iou, const float* __restrict__ b_f,
    float* __restrict__ h_g, half_t* __restrict__ c_ws,
    unsigned short* __restrict__ h_bf)
{
    __shared__ __align__(16) unsigned short A_lds[MT * H2];
    const int tid = threadIdx.x;
    const int w = tid >> 6, lr = tid & 15, lc = (tid & 63) >> 4;
    const int ee = w * 16 + lr;
    const float bi = b_iou[ee], bo = b_iou[HH + ee], bu = b_iou[2 * HH + ee];
    const float bl = b_f[ee],   br = b_f[HH + ee];
    do_tile(lvl, blockIdx.x, bi, bo, bu, bl, br, h_g, c_ws, h_bf, A_lds, tid, w, lr, lc, ee);
}

// ---------------- fused 2-level pair: B=lb (tiles 2b,2b+1), M=lb-1 (tile b) ----------------
// Children of M tile b are exactly flat B nodes [64b,64b+64) = the block's two B
// tiles. B outputs: h -> LDS (M's A-layout) + h_g; c -> global f16 (L2-hot for M).
// Only M writes h_bf. LDS 32 KB -> 4 blocks/CU.
__global__ __launch_bounds__(TPB, 4) void fuse2_k(
    int lb,
    const float* __restrict__ b_iou, const float* __restrict__ b_f,
    float* __restrict__ h_g, half_t* __restrict__ c_ws,
    unsigned short* __restrict__ h_bf)
{
    __shared__ __align__(16) unsigned char As[16384];   // B staging
    __shared__ __align__(16) unsigned char hm[16384];   // B h outputs in M A-layout

    const int tid = threadIdx.x;
    const int w = tid >> 6, lr = tid & 15, lc = (tid & 63) >> 4;
    const int ee = w * 16 + lr;
    const int b  = blockIdx.x;
    const int lm = lb - 1;
    const int bmask = (1 << lb) - 1, mmask = (1 << lm) - 1;
    const float bi = b_iou[ee], bo = b_iou[HH + ee], bu = b_iou[2 * HH + ee];
    const float bl = b_f[ee],   br = b_f[HH + ee];
    const unsigned short* Wp = Wb_g + (size_t)ee * H2 + lc * 8;

#pragma unroll 1
    for (int ib = 0; ib < 2; ++ib) {
        __syncthreads();   // As free (prev MFMA done)

#pragma unroll
        for (int it = 0; it < 2; ++it) {
            int item = tid + TPB * it;
            int m = item >> 5, u = item & 31;
            int node = b * 64 + ib * 32 + m;
            int tree = node >> lb;
            int loc  = bmask + (node & bmask);
            size_t crow = (size_t)tree * NPT + 2 * loc + 1 + (u >> 4);
            uint4 v = *(const uint4*)(h_bf + crow * HH + (u & 15) * 8);
            *(uint4*)(As + swz(m * 512 + u * 16)) = v;
        }
        __syncthreads();

        f32x4 acc[2][5] = {};
        mfma_from(As, Wp, acc, lr, lc);

        float clv[2][4], crv[2][4];
#pragma unroll
        for (int mt = 0; mt < 2; ++mt)
#pragma unroll
            for (int r = 0; r < 4; ++r) {
                int node = b * 64 + ib * 32 + mt * 16 + lc * 4 + r;
                int tree = node >> lb;
                int loc  = bmask + (node & bmask);
                size_t lrow = (size_t)tree * NPT + 2 * loc + 1;
                clv[mt][r] = (float)c_ws[lrow * HH + ee];
                crv[mt][r] = (float)c_ws[(lrow + 1) * HH + ee];
            }

#pragma unroll
        for (int mt = 0; mt < 2; ++mt)
#pragma unroll
            for (int r = 0; r < 4; ++r) {
                int n_local = ib * 32 + mt * 16 + lc * 4 + r;
                int node = b * 64 + n_local;
                int tree = node >> lb;
                int loc  = bmask + (node & bmask);
                size_t row = (size_t)tree * NPT + loc;
                float hv, cv;
                GATES(acc, mt, r, clv[mt][r], crv[mt][r], hv, cv);
                h_g[row * HH + ee]  = hv;
                c_ws[row * HH + ee] = (half_t)cv;
                int m_in = n_local >> 1, half = n_local & 1;
                *(unsigned short*)(hm + swz(m_in * 512 + ((half << 7) + ee) * 2)) = f2bf(hv);
            }
    }

    // ---- M tile b: children h from LDS, c from L2-hot global ----
    __syncthreads();
    {
        f32x4 acc[2][5] = {};
        mfma_from(hm, Wp, acc, lr, lc);

        float clv[2][4], crv[2][4];
#pragma unroll
        for (int mt = 0; mt < 2; ++mt)
#pragma unroll
            for (int r = 0; r < 4; ++r) {
                int n_m  = b * 32 + mt * 16 + lc * 4 + r;
                int tree = n_m >> lm;
                int loc  = mmask + (n_m & mmask);
                size_t lrow = (size_t)tree * NPT + 2 * loc + 1;
                clv[mt][r] = (float)c_ws[lrow * HH + ee];
                crv[mt][r] = (float)c_ws[(lrow + 1) * HH + ee];
            }
#pragma unroll
        for (int mt = 0; mt < 2; ++mt)
#pragma unroll
            for (int r = 0; r < 4; ++r) {
                int n_m  = b * 32 + mt * 16 + lc * 4 + r;
                int tree = n_m >> lm;
                int loc  = mmask + (n_m & mmask);
                size_t row = (size_t)tree * NPT + loc;
                float hv, cv;
                GATES(acc, mt, r, clv[mt][r], crv[mt][r], hv, cv);
                h_g[row * HH + ee]  = hv;
                c_ws[row * HH + ee] = (half_t)cv;
                h_bf[row * HH + ee] = f2bf(hv);
            }
    }
}

// ---------------- solo tail l=5..0: one block per tree, weights in registers ----------------
__global__ __launch_bounds__(TPB, 2) void solo_k(
    const float* __restrict__ b_iou, const float* __restrict__ b_f,
    float* __restrict__ h_g, half_t* __restrict__ c_ws,
    const unsigned short* __restrict__ h_bf)
{
    __shared__ __align__(16) unsigned char hb[32768];

    const int tid = threadIdx.x;
    const int w = tid >> 6, lr = tid & 15, lc = (tid & 63) >> 4;
    const int ee = w * 16 + lr;
    const size_t tb = (size_t)blockIdx.x * NPT;
    const float bi = b_iou[ee], bo = b_iou[HH + ee], bu = b_iou[2 * HH + ee];
    const float bl = b_f[ee],   br = b_f[HH + ee];

    bf16x8 Bf[5][8];
    const unsigned short* Wp = Wb_g + (size_t)ee * H2 + lc * 8;
#pragma unroll
    for (int g = 0; g < 5; ++g)
#pragma unroll
        for (int kk = 0; kk < 8; ++kk)
            Bf[g][kk] = *(const bf16x8*)(Wp + (size_t)g * HH * H2 + kk * 32);

#pragma unroll
    for (int it = 0; it < 2; ++it) {
        int p = tid + TPB * it;
        int cc = p >> 4, q = p & 15;
        uint4 v = *(const uint4*)(h_bf + (tb + 63 + cc) * HH + q * 8);
        *(uint4*)(hb + swz(p * 16)) = v;
    }

#pragma unroll 1
    for (int l = 5; l >= 0; --l) {
        const int nl     = 1 << l;
        const int loc0   = nl - 1;
        const int cloc0  = 2 * nl - 1;
        const int cbase  = (l & 1) ? 0 : 16384;
        const int obase  = cbase ^ 16384;
        const bool mt1   = (nl > 16);

        __syncthreads();

        f32x4 acc[2][5] = {};
#pragma unroll
        for (int kk = 0; kk < 8; ++kk) {
            bf16x8 a0 = *(const bf16x8*)(hb + cbase + swz(lr * 512 + kk * 64 + lc * 16));
#pragma unroll
            for (int g = 0; g < 5; ++g)
                acc[0][g] = __builtin_amdgcn_mfma_f32_16x16x32_bf16(a0, Bf[g][kk], acc[0][g], 0, 0, 0);
            if (mt1) {
                bf16x8 a1 = *(const bf16x8*)(hb + cbase + swz((16 + lr) * 512 + kk * 64 + lc * 16));
#pragma unroll
                for (int g = 0; g < 5; ++g)
                    acc[1][g] = __builtin_amdgcn_mfma_f32_16x16x32_bf16(a1, Bf[g][kk], acc[1][g], 0, 0, 0);
            }
        }
        __syncthreads();

#pragma unroll
        for (int mt = 0; mt < 2; ++mt)
#pragma unroll
            for (int r = 0; r < 4; ++r) {
                int j = mt * 16 + lc * 4 + r;
                if (j >= nl) continue;
                size_t row  = tb + loc0 + j;
                size_t lrow = tb + cloc0 + 2 * j;
                float hv, cv;
                GATES(acc, mt, r, (float)c_ws[lrow * HH + ee], (float)c_ws[(lrow + 1) * HH + ee], hv, cv);
                h_g[row * HH + ee]  = hv;
                c_ws[row * HH + ee] = (half_t)cv;
                *(unsigned short*)(hb + obase + swz(j * 256 + ee * 2)) = f2bf(hv);
            }
    }
}

extern "C" void kernel_launch(void* const* d_in, const int* in_sizes, int n_in,
                              void* d_out, int out_size, void* d_ws, size_t ws_size,
                              hipStream_t stream)
{
    const float* iou   = (const float*)d_in[0];
    const float* c_in  = (const float*)d_in[2];
    const float* W_iou = (const float*)d_in[3];
    const float* b_iou = (const float*)d_in[4];
    const float* W_f   = (const float*)d_in[5];
    const float* b_f   = (const float*)d_in[6];
    float* h_out = (float*)d_out;
    half_t* c_ws = (half_t*)d_ws;                                                       // 67 MiB f16 c
    unsigned short* h_bf = (unsigned short*)((char*)d_ws + (size_t)72 * 1024 * 1024);   // 67 MiB bf16 h

    conv_k<<<160, 256, 0, stream>>>(W_iou, W_f);
    leaf_k<<<16384, 256, 0, stream>>>(iou, c_in, b_iou, h_out, c_ws, h_bf);

    fuse2_k<<<1024, TPB, 0, stream>>>(14, b_iou, b_f, h_out, c_ws, h_bf);  // l=14,13
    fuse2_k<<< 256, TPB, 0, stream>>>(12, b_iou, b_f, h_out, c_ws, h_bf);  // l=12,11
    fuse2_k<<<  64, TPB, 0, stream>>>(10, b_iou, b_f, h_out, c_ws, h_bf);  // l=10,9
    fuse2_k<<<  16, TPB, 0, stream>>>( 8, b_iou, b_f, h_out, c_ws, h_bf);  // l=8,7
    level_k<<<   8, TPB, 0, stream>>>( 6, b_iou, b_f, h_out, c_ws, h_bf);  // l=6
    solo_k <<<   4, TPB, 0, stream>>>(b_iou, b_f, h_out, c_ws, h_bf);      // l=5..0
}

// Round 10
// 361.648 us; speedup vs baseline: 1.7376x; 1.3404x over previous
//
#include <hip/hip_runtime.h>

#define HH   128
#define H2   256
#define H3   384
#define NPT  65535      // nodes per tree (2^16 - 1)
#define MT   32         // nodes per tile
#define TPB  512        // 8 waves

typedef __bf16    bf16x8 __attribute__((ext_vector_type(8)));
typedef float     f32x4  __attribute__((ext_vector_type(4)));
typedef _Float16  f16x4  __attribute__((ext_vector_type(4)));
typedef _Float16  half_t;

__device__ unsigned short Wb_g[640 * 256];   // bf16 [row=output col j][k]; j<384: W_iou, else W_f

__device__ __forceinline__ float fsig(float x)  { return 1.0f / (1.0f + __expf(-x)); }
__device__ __forceinline__ float ftanh(float x) { return 1.0f - 2.0f / (__expf(2.0f * x) + 1.0f); }
__device__ __forceinline__ unsigned short f2bf(float f) {   // RNE fp32->bf16
    unsigned u = __float_as_uint(f);
    u += 0x7fffu + ((u >> 16) & 1u);
    return (unsigned short)(u >> 16);
}
__device__ __forceinline__ int swz(int off) { return off ^ (((off >> 9) & 7) << 4); }

// ---------------- weight convert ----------------
__global__ __launch_bounds__(256) void conv_k(const float* __restrict__ W_iou,
                                              const float* __restrict__ W_f)
{
    int t    = blockIdx.x * 256 + threadIdx.x;
    int base = t * 4;
    int j = base >> 8, k = base & 255;
    const float* src = (j < H3) ? (W_iou + j * H2 + k)
                                : (W_f + (j - H3) * H2 + k);
    float4 v = *(const float4*)src;
    ushort4 p;
    p.x = f2bf(v.x); p.y = f2bf(v.y); p.z = f2bf(v.z); p.w = f2bf(v.w);
    *(ushort4*)(Wb_g + base) = p;
}

// ---------------- leaf frontier ----------------
__global__ __launch_bounds__(256) void leaf_k(
    const float* __restrict__ iou, const float* __restrict__ c_in,
    const float* __restrict__ b_iou,
    float* __restrict__ h_out, half_t* __restrict__ c_ws,
    unsigned short* __restrict__ h_bf)
{
    int g    = blockIdx.x * 256 + threadIdx.x;
    int node = g >> 5;                           // 131072 leaf nodes
    int e    = (g & 31) << 2;
    int tree = node >> 15;
    int loc  = 32767 + (node & 32767);
    int row  = tree * NPT + loc;                 // fits int (max 262139)

    const float* ip = iou + (size_t)row * H3;    // row*384 ~ 100M: use size_t for safety of *4B
    float4 vi = *(const float4*)(ip + e);
    float4 vo = *(const float4*)(ip + HH + e);
    float4 vu = *(const float4*)(ip + 2 * HH + e);
    float4 vc = *(const float4*)(c_in + row * HH + e);
    float4 bi = *(const float4*)(b_iou + e);
    float4 bo = *(const float4*)(b_iou + HH + e);
    float4 bu = *(const float4*)(b_iou + 2 * HH + e);

    float4 hn, cn;
#define DOL(X) { float iv = fsig(vi.X + bi.X); float ov = fsig(vo.X + bo.X); \
                 float uv = ftanh(vu.X + bu.X); float cv = iv * uv + vc.X;   \
                 cn.X = cv; hn.X = ov * ftanh(cv); }
    DOL(x) DOL(y) DOL(z) DOL(w)
#undef DOL
    *(float4*)(h_out + row * HH + e) = hn;
    f16x4 cf; cf.x = (half_t)cn.x; cf.y = (half_t)cn.y; cf.z = (half_t)cn.z; cf.w = (half_t)cn.w;
    *(f16x4*)(c_ws + row * HH + e) = cf;
    ushort4 hb;
    hb.x = f2bf(hn.x); hb.y = f2bf(hn.y); hb.z = f2bf(hn.z); hb.w = f2bf(hn.w);
    *(ushort4*)(h_bf + row * HH + e) = hb;
}

// ---------------- MFMA over one 32-node swizzled LDS tile ----------------
__device__ __forceinline__ void mfma_from(const unsigned char* tile,
                                          const unsigned short* Wp,
                                          f32x4 acc[2][5], int lr, int lc)
{
#pragma unroll
    for (int kk = 0; kk < 8; ++kk) {
        bf16x8 a0 = *(const bf16x8*)(tile + swz(lr * 512 + kk * 64 + lc * 16));
        bf16x8 a1 = *(const bf16x8*)(tile + swz((16 + lr) * 512 + kk * 64 + lc * 16));
#pragma unroll
        for (int g = 0; g < 5; ++g) {
            bf16x8 b = *(const bf16x8*)(Wp + g * HH * H2 + kk * 32);
            acc[0][g] = __builtin_amdgcn_mfma_f32_16x16x32_bf16(a0, b, acc[0][g], 0, 0, 0);
            acc[1][g] = __builtin_amdgcn_mfma_f32_16x16x32_bf16(a1, b, acc[1][g], 0, 0, 0);
        }
    }
}

#define GATES(AC, MTI, RI, CL, CR, HV, CV) \
    { float pi = AC[MTI][0][RI] + bi, po = AC[MTI][1][RI] + bo, pu = AC[MTI][2][RI] + bu; \
      float pl = AC[MTI][3][RI] + bl, pr = AC[MTI][4][RI] + br;                           \
      CV = fsig(pi) * ftanh(pu) + fsig(pl) * (CL) + fsig(pr) * (CR);                      \
      HV = fsig(po) * ftanh(CV); }

// ---------------- one 32-node tile, 32-bit addressing, c-loads before MFMA ----------------
__device__ __forceinline__ void do_tile(
    int lvl, int tile,
    float bi, float bo, float bu, float bl, float br,
    float* __restrict__ h_g, half_t* __restrict__ c_ws,
    unsigned short* __restrict__ h_bf,
    unsigned short* A_lds,
    int tid, int w, int lr, int lc, int ee)
{
    const int node0 = tile * MT;
    const int loc0  = (1 << lvl) - 1;
    const int lmask = loc0;

    __syncthreads();   // prior tile's LDS reads complete before restage

    // ---- stage children h (bf16) into swizzled LDS; 32-bit offsets ----
#pragma unroll
    for (int it = 0; it < 2; ++it) {
        int item = tid + TPB * it;
        int m = item >> 5, u = item & 31;
        int node = node0 + m;
        int tree = node >> lvl;
        int loc  = loc0 + (node & lmask);
        int coff = (tree * NPT + 2 * loc + 1 + (u >> 4)) * HH + (u & 15) * 8;
        uint4 v = *(const uint4*)(h_bf + coff);
        *(uint4*)((char*)A_lds + swz(m * 512 + u * 16)) = v;
    }
    __syncthreads();

    // ---- output offsets once; issue all 16 child-c loads BEFORE the MFMA loop ----
    int   rofs[2][4];
    float clv[2][4], crv[2][4];
#pragma unroll
    for (int mt = 0; mt < 2; ++mt)
#pragma unroll
        for (int r = 0; r < 4; ++r) {
            int node = node0 + mt * 16 + lc * 4 + r;
            int tree = node >> lvl;
            int loc  = loc0 + (node & lmask);
            int base = tree * NPT + loc;          // node row
            int lrow = base + loc + 1;            // = tree*NPT + 2*loc+1 (mul-free)
            rofs[mt][r] = base * HH + ee;
            clv[mt][r] = (float)c_ws[lrow * HH + ee];
            crv[mt][r] = (float)c_ws[lrow * HH + HH + ee];
        }

    f32x4 acc[2][5] = {};
    const unsigned short* Wp = Wb_g + ee * H2 + lc * 8;
    mfma_from((const unsigned char*)A_lds, Wp, acc, lr, lc);

#pragma unroll
    for (int mt = 0; mt < 2; ++mt)
#pragma unroll
        for (int r = 0; r < 4; ++r) {
            float hv, cv;
            GATES(acc, mt, r, clv[mt][r], crv[mt][r], hv, cv);
            int o = rofs[mt][r];
            h_g[o]  = hv;
            c_ws[o] = (half_t)cv;
            h_bf[o] = f2bf(hv);
        }
}

// ---------------- single level ----------------
__global__ __launch_bounds__(TPB, 4) void level_k(
    int lvl,
    const float* __restrict__ b_iou, const float* __restrict__ b_f,
    float* __restrict__ h_g, half_t* __restrict__ c_ws,
    unsigned short* __restrict__ h_bf)
{
    __shared__ __align__(16) unsigned short A_lds[MT * H2];
    const int tid = threadIdx.x;
    const int w = tid >> 6, lr = tid & 15, lc = (tid & 63) >> 4;
    const int ee = w * 16 + lr;
    const float bi = b_iou[ee], bo = b_iou[HH + ee], bu = b_iou[2 * HH + ee];
    const float bl = b_f[ee],   br = b_f[HH + ee];
    do_tile(lvl, blockIdx.x, bi, bo, bu, bl, br, h_g, c_ws, h_bf, A_lds, tid, w, lr, lc, ee);
}

// ---------------- solo tail l=5..0: one block per tree, weights in registers ----------------
__global__ __launch_bounds__(TPB, 2) void solo_k(
    const float* __restrict__ b_iou, const float* __restrict__ b_f,
    float* __restrict__ h_g, half_t* __restrict__ c_ws,
    const unsigned short* __restrict__ h_bf)
{
    __shared__ __align__(16) unsigned char hb[32768];

    const int tid = threadIdx.x;
    const int w = tid >> 6, lr = tid & 15, lc = (tid & 63) >> 4;
    const int ee = w * 16 + lr;
    const int tb = blockIdx.x * NPT;
    const float bi = b_iou[ee], bo = b_iou[HH + ee], bu = b_iou[2 * HH + ee];
    const float bl = b_f[ee],   br = b_f[HH + ee];

    bf16x8 Bf[5][8];
    const unsigned short* Wp = Wb_g + ee * H2 + lc * 8;
#pragma unroll
    for (int g = 0; g < 5; ++g)
#pragma unroll
        for (int kk = 0; kk < 8; ++kk)
            Bf[g][kk] = *(const bf16x8*)(Wp + g * HH * H2 + kk * 32);

#pragma unroll
    for (int it = 0; it < 2; ++it) {
        int p = tid + TPB * it;
        int cc = p >> 4, q = p & 15;
        uint4 v = *(const uint4*)(h_bf + (tb + 63 + cc) * HH + q * 8);
        *(uint4*)(hb + swz(p * 16)) = v;
    }

#pragma unroll 1
    for (int l = 5; l >= 0; --l) {
        const int nl     = 1 << l;
        const int loc0   = nl - 1;
        const int cloc0  = 2 * nl - 1;
        const int cbase  = (l & 1) ? 0 : 16384;
        const int obase  = cbase ^ 16384;
        const bool mt1   = (nl > 16);

        __syncthreads();

        f32x4 acc[2][5] = {};
#pragma unroll
        for (int kk = 0; kk < 8; ++kk) {
            bf16x8 a0 = *(const bf16x8*)(hb + cbase + swz(lr * 512 + kk * 64 + lc * 16));
#pragma unroll
            for (int g = 0; g < 5; ++g)
                acc[0][g] = __builtin_amdgcn_mfma_f32_16x16x32_bf16(a0, Bf[g][kk], acc[0][g], 0, 0, 0);
            if (mt1) {
                bf16x8 a1 = *(const bf16x8*)(hb + cbase + swz((16 + lr) * 512 + kk * 64 + lc * 16));
#pragma unroll
                for (int g = 0; g < 5; ++g)
                    acc[1][g] = __builtin_amdgcn_mfma_f32_16x16x32_bf16(a1, Bf[g][kk], acc[1][g], 0, 0, 0);
            }
        }
        __syncthreads();

#pragma unroll
        for (int mt = 0; mt < 2; ++mt)
#pragma unroll
            for (int r = 0; r < 4; ++r) {
                int j = mt * 16 + lc * 4 + r;
                if (j >= nl) continue;
                int row  = tb + loc0 + j;
                int lrow = tb + cloc0 + 2 * j;
                float hv, cv;
                GATES(acc, mt, r, (float)c_ws[lrow * HH + ee], (float)c_ws[lrow * HH + HH + ee], hv, cv);
                h_g[row * HH + ee]  = hv;
                c_ws[row * HH + ee] = (half_t)cv;
                *(unsigned short*)(hb + obase + swz(j * 256 + ee * 2)) = f2bf(hv);
            }
    }
}

extern "C" void kernel_launch(void* const* d_in, const int* in_sizes, int n_in,
                              void* d_out, int out_size, void* d_ws, size_t ws_size,
                              hipStream_t stream)
{
    const float* iou   = (const float*)d_in[0];
    const float* c_in  = (const float*)d_in[2];
    const float* W_iou = (const float*)d_in[3];
    const float* b_iou = (const float*)d_in[4];
    const float* W_f   = (const float*)d_in[5];
    const float* b_f   = (const float*)d_in[6];
    float* h_out = (float*)d_out;
    half_t* c_ws = (half_t*)d_ws;                                                       // 67 MiB f16 c
    unsigned short* h_bf = (unsigned short*)((char*)d_ws + (size_t)72 * 1024 * 1024);   // 67 MiB bf16 h

    conv_k<<<160, 256, 0, stream>>>(W_iou, W_f);
    leaf_k<<<16384, 256, 0, stream>>>(iou, c_in, b_iou, h_out, c_ws, h_bf);

    for (int l = 14; l >= 6; --l) {
        int blocks = (4 << l) / MT;
        level_k<<<blocks, TPB, 0, stream>>>(l, b_iou, b_f, h_out, c_ws, h_bf);
    }
    solo_k<<<4, TPB, 0, stream>>>(b_iou, b_f, h_out, c_ws, h_bf);
}